// Round 6
// baseline (105.839 us; speedup 1.0000x reference)
//
#include <hip/hip_runtime.h>
#include <math.h>

// Correctly-rounded double constants: Cj = cos(j*pi/16), N0 = sqrt(1/8).
#define C1 0.9807852804032304
#define C2 0.9238795325112867
#define C3 0.8314696123025452
#define C4 0.7071067811865476
#define C5 0.5555702330196022
#define C6 0.3826834323650898
#define C7 0.19509032201612825
#define N0 0.35355339059327373

// DCT-II matrix M[k][n] = norm_k * cos(pi/8*(n+0.5)*k), fully compile-time.
static constexpr double Mc[8][8] = {
 {  N0,      N0,      N0,      N0,      N0,      N0,      N0,      N0    },
 {  .5*C1,   .5*C3,   .5*C5,   .5*C7,  -.5*C7,  -.5*C5,  -.5*C3,  -.5*C1 },
 {  .5*C2,   .5*C6,  -.5*C6,  -.5*C2,  -.5*C2,  -.5*C6,   .5*C6,   .5*C2 },
 {  .5*C3,  -.5*C7,  -.5*C1,  -.5*C5,   .5*C5,   .5*C1,   .5*C7,  -.5*C3 },
 {  .5*C4,  -.5*C4,  -.5*C4,   .5*C4,   .5*C4,  -.5*C4,  -.5*C4,   .5*C4 },
 {  .5*C5,  -.5*C1,   .5*C7,   .5*C3,  -.5*C3,  -.5*C7,   .5*C1,  -.5*C5 },
 {  .5*C6,  -.5*C2,   .5*C2,  -.5*C6,  -.5*C6,   .5*C2,  -.5*C2,   .5*C6 },
 {  .5*C7,  -.5*C5,   .5*C3,  -.5*C1,   .5*C1,  -.5*C3,   .5*C5,  -.5*C7 },
};
// f32 copy for the post-quantization (smooth) path.
#define ROWF(r) {(float)Mc[r][0],(float)Mc[r][1],(float)Mc[r][2],(float)Mc[r][3],\
                 (float)Mc[r][4],(float)Mc[r][5],(float)Mc[r][6],(float)Mc[r][7]}
static constexpr float Mcf[8][8] = {ROWF(0),ROWF(1),ROWF(2),ROWF(3),ROWF(4),ROWF(5),ROWF(6),ROWF(7)};

// JPEG base quantization tables (exact integers)
static __device__ const double LUM_BASE[64] = {
 16,11,10,16,24,40,51,61,
 12,12,14,19,26,58,60,55,
 14,13,16,24,40,57,69,56,
 14,17,22,29,51,87,80,62,
 18,22,37,56,68,109,103,77,
 24,35,55,64,81,104,113,92,
 49,64,78,87,103,121,120,101,
 72,92,95,98,112,100,103,99};
static __device__ const double CHROM_BASE[64] = {
 17,18,24,47,99,99,99,99,
 18,21,26,66,99,99,99,99,
 24,26,56,99,99,99,99,99,
 47,66,99,99,99,99,99,99,
 99,99,99,99,99,99,99,99,
 99,99,99,99,99,99,99,99,
 99,99,99,99,99,99,99,99,
 99,99,99,99,99,99,99,99};

// Wave-level LDS fence: pins compiler ordering (memory clobber) AND drains
// LDS ops (lgkmcnt). Replaces __syncthreads() for 1-wave blocks. With the
// U64/U32 overlay (union), EVERY cross-phase LDS hazard pair is separated
// by one of these — correctness does not depend on TBAA.
#define WAVE_FENCE() asm volatile("s_waitcnt lgkmcnt(0)" ::: "memory")

// Round 14: 105.1us. Round 15 (this): occupancy 4 -> 5 waves/SIMD —
// - U64 (f64 T1) and U32 (f32 T2) are NEVER simultaneously live per channel
//   -> overlay them in a union: LDS 8.96KB -> 6.5KB/block (24 blocks LDS cap).
//   Extra fence after the t1 reads pins T2 writes below them (R3 lesson:
//   never let cross-typed LDS ordering rest on TBAA).
// - __launch_bounds__(64,5): VGPR cap 102 (est. peak ~90-100, no spill),
//   20 blocks/CU -> 5 waves/SIMD.
// Same values, same expression trees -> bit-identical output.
__global__ __launch_bounds__(64, 5) void jpeg_fwd(const float* __restrict__ img,
                                                  const int* __restrict__ quality,
                                                  float* __restrict__ out)
{
    __shared__ double QR[256];     // [2][8][8][2] = interleaved {q, 1/q}, 2048 B
    union UBuf {
        double d64[576];           // f64 transpose-1 view (pad-9), 4608 B
        float  f32[576];           // f32 transpose-2 view (pad-9), first 2304 B
    };
    __shared__ UBuf UB;            // overlaid: phases never simultaneously live

    const int l   = threadIdx.x;   // 0..63
    const int blk = l >> 3;        // block within strip (0..7)
    const int rr  = l & 7;         // row within block

    const int b    = blockIdx.x >> 9;   // image index
    const int rem  = blockIdx.x & 511;
    const int row0 = (rem >> 3) << 3;   // strip row * 8
    const int col0 = (rem & 7) << 6;    // strip col * 64

    const size_t plane = 512 * 512;

    // ---- Issue global loads early (my row's 8 px, all 3 planes, float4)
    const float* p = img + (size_t)(b * 3) * plane + (size_t)(row0 + rr) * 512 + col0 + blk * 8;
    float4 R0 = *(const float4*)(p);
    float4 R1 = *(const float4*)(p + 4);
    float4 G0 = *(const float4*)(p + plane);
    float4 G1 = *(const float4*)(p + plane + 4);
    float4 B0 = *(const float4*)(p + 2 * plane);
    float4 B1 = *(const float4*)(p + 2 * plane + 4);

    // ---- Build quant table + reciprocals in LDS — all 64 lanes, 2 entries
    // each (R0 pattern). Cross-lane RAW protected by the wave fence below.
    // Arithmetic identical to previous rounds -> bit-identical {q, 1/q}.
    {
        int q = quality[0];
        q = q < 1 ? 1 : (q > 100 ? 100 : q);
        double scale = (q < 50) ? (5000.0 / (double)q) : (200.0 - 2.0 * (double)q);
        #pragma unroll
        for (int h = 0; h < 2; ++h) {
            int e = l + (h << 6);           // entries l and l+64 -> covers 0..127
            int tbl = e >> 6, idx = e & 63;
            double base = tbl ? CHROM_BASE[idx] : LUM_BASE[idx];
            double v = (base * scale + 50.0) / 100.0;
            v = fmin(fmax(v, 1.0), 255.0);
            QR[2 * e]     = v;
            QR[2 * e + 1] = 1.0 / v;
        }
    }
    WAVE_FENCE();   // QR visible to all lanes of this (only) wave

    // YCbCr weights with x255 folded in at compile time (f64 products).
    const double F00 =  0.299 * 255.0,  F01 =  0.587 * 255.0,  F02 =  0.114 * 255.0;
    const double F10 = -0.1687 * 255.0, F11 = -0.3313 * 255.0, F12 =  0.5 * 255.0;
    const double F20 =  0.5 * 255.0,    F21 = -0.4187 * 255.0, F22 = -0.0813 * 255.0;

    float rf[8] = {R0.x, R0.y, R0.z, R0.w, R1.x, R1.y, R1.z, R1.w};
    float gf[8] = {G0.x, G0.y, G0.z, G0.w, G1.x, G1.y, G1.z, G1.w};
    float bf[8] = {B0.x, B0.y, B0.z, B0.w, B1.x, B1.y, B1.z, B1.w};

    float pix0[8], pix1[8], pix2[8];   // final IDCT pixel rows Y, Cb, Cr

    // ================= per-channel pipeline (macro: CIDX is a literal) =====
    // LDS hazard ordering (overlay-safe): every conflicting pair below is
    // separated by a WAVE_FENCE:
    //   T1w(f64) |F| t1r(f64) |F| ... T2w(f32) |F| tCr(f32) |F| next T1w
#define CHANNEL_BODY(CIDX, PIXARR, COLOR_EXPR)                                  \
    {                                                                           \
        /* quant-table base for this channel (reference's flattened quirk) */   \
        const int sel_c = ((b * 3 + CIDX) < 16) ? 0 : 1;                        \
        const double* QRb = QR + (((sel_c << 6) + rr) << 1);                    \
        /* ---- Color convert (f64), keep +128 then -128 (both roundings) */   \
        double row[8];                                                          \
        _Pragma("unroll")                                                       \
        for (int k = 0; k < 8; ++k) {                                           \
            double rv = (double)rf[k];                                          \
            double gv = (double)gf[k];                                          \
            double bv = (double)bf[k];                                          \
            double v  = (COLOR_EXPR);                                           \
            row[k] = v - 128.0;                                                 \
        }                                                                       \
        /* ---- P1: row @ M^T via even-odd symmetry (f64) */                    \
        double y[8];                                                            \
        {                                                                       \
            double u0[4], v0[4];                                                \
            _Pragma("unroll")                                                   \
            for (int k = 0; k < 4; ++k) {                                       \
                u0[k] = row[k] + row[7 - k];                                    \
                v0[k] = row[k] - row[7 - k];                                    \
            }                                                                   \
            _Pragma("unroll")                                                   \
            for (int c = 0; c < 8; c += 2) {                                    \
                double se = 0.0, so = 0.0;                                      \
                _Pragma("unroll")                                               \
                for (int k = 0; k < 4; ++k) {                                   \
                    se += u0[k] * Mc[c][k];                                     \
                    so += v0[k] * Mc[c + 1][k];                                 \
                }                                                               \
                y[c] = se; y[c + 1] = so;                                       \
            }                                                                   \
        }                                                                       \
        /* ---- Transpose 1 (f64, pad-9, in-wave, fenced) */                    \
        {                                                                       \
            double* tb = UB.d64 + blk * 72 + rr * 9;                            \
            _Pragma("unroll")                                                   \
            for (int k = 0; k < 8; ++k) tb[k] = y[k];                           \
        }                                                                       \
        WAVE_FENCE();                                                           \
        double t1[8];                                                           \
        {                                                                       \
            const double* tb = UB.d64 + blk * 72 + rr;                          \
            _Pragma("unroll")                                                   \
            for (int k = 0; k < 8; ++k) t1[k] = tb[k * 9];                      \
        }                                                                       \
        WAVE_FENCE(); /* overlay WAR: T2 (f32) writes must stay below t1 reads */\
        /* ---- P2: column DCT (even-odd) + quantize tq = rint(s/q)*q.       */ \
        /* {q, 1/q} fetched per-j as one 16B LDS broadcast read (8 distinct  */ \
        /* addresses, 8-lane broadcast groups -> conflict-free).             */ \
        double wq[8];                                                           \
        {                                                                       \
            double tu[4], tv[4];                                                \
            _Pragma("unroll")                                                   \
            for (int k = 0; k < 4; ++k) {                                       \
                tu[k] = t1[k] + t1[7 - k];                                      \
                tv[k] = t1[k] - t1[7 - k];                                      \
            }                                                                   \
            _Pragma("unroll")                                                   \
            for (int j = 0; j < 8; j += 2) {                                    \
                double se = 0.0, so = 0.0;                                      \
                _Pragma("unroll")                                               \
                for (int k = 0; k < 4; ++k) {                                   \
                    se += tu[k] * Mc[j][k];                                     \
                    so += tv[k] * Mc[j + 1][k];                                 \
                }                                                               \
                { /* even j: Markstein reciprocal division, bit-identical */    \
                    double q = QRb[(j << 4)];                                   \
                    double r = QRb[(j << 4) + 1];                               \
                    double qh = se * r;                                         \
                    double e  = fma(-q, qh, se);                                \
                    double qq = fma(e, r, qh);                                  \
                    wq[j] = rint(qq) * q;                                       \
                }                                                               \
                { /* odd j */                                                   \
                    double q = QRb[((j + 1) << 4)];                             \
                    double r = QRb[((j + 1) << 4) + 1];                         \
                    double qh = so * r;                                         \
                    double e  = fma(-q, qh, so);                                \
                    double qq = fma(e, r, qh);                                  \
                    wq[j + 1] = rint(qq) * q;                                   \
                }                                                               \
            }                                                                   \
        }                                                                       \
        /* ======== post-cliff: f32 ======== */                                 \
        float wqf[8];                                                           \
        _Pragma("unroll")                                                       \
        for (int k = 0; k < 8; ++k) wqf[k] = (float)wq[k];                      \
        /* ---- P3: (tq^T row) @ M (f32, even-odd over output index j) */       \
        float a3[8];                                                            \
        _Pragma("unroll")                                                       \
        for (int j = 0; j < 4; ++j) {                                           \
            float pe = 0.0f, po = 0.0f;                                         \
            _Pragma("unroll")                                                   \
            for (int k = 0; k < 4; ++k) {                                       \
                pe += wqf[2 * k]     * Mcf[2 * k][j];                           \
                po += wqf[2 * k + 1] * Mcf[2 * k + 1][j];                       \
            }                                                                   \
            a3[j]     = pe + po;                                                \
            a3[7 - j] = pe - po;                                                \
        }                                                                       \
        /* ---- Transpose 2 (f32, pad-9, in-wave, fenced; overlaid buffer) */   \
        {                                                                       \
            float* tb = UB.f32 + blk * 72 + rr * 9;                             \
            _Pragma("unroll")                                                   \
            for (int k = 0; k < 8; ++k) tb[k] = a3[k];                          \
        }                                                                       \
        WAVE_FENCE();                                                           \
        float tC[8];                                                            \
        {                                                                       \
            const float* c2 = UB.f32 + blk * 72 + rr;                           \
            _Pragma("unroll")                                                   \
            for (int k = 0; k < 8; ++k) tC[k] = c2[k * 9];                      \
        }                                                                       \
        /* ---- P4 (f32, even-odd): final IDCT row rr for this channel */       \
        _Pragma("unroll")                                                       \
        for (int j = 0; j < 4; ++j) {                                           \
            float e = 0.0f, o = 0.0f;                                           \
            _Pragma("unroll")                                                   \
            for (int k = 0; k < 4; ++k) {                                       \
                e += tC[2 * k]     * Mcf[2 * k][j];                             \
                o += tC[2 * k + 1] * Mcf[2 * k + 1][j];                         \
            }                                                                   \
            PIXARR[j]     = e + o;                                              \
            PIXARR[7 - j] = e - o;                                              \
        }                                                                       \
        WAVE_FENCE(); /* WAR: next channel's T1 (f64) writes stay below tC reads */\
    }

    CHANNEL_BODY(0, pix0, F00 * rv + F01 * gv + F02 * bv)
    CHANNEL_BODY(1, pix1, F10 * rv + F11 * gv + F12 * bv + 128.0)
    CHANNEL_BODY(2, pix2, F20 * rv + F21 * gv + F22 * bv + 128.0)
#undef CHANNEL_BODY

    // ---- Color back (f32), all in registers; exact same expression trees.
    float oR[8], oG[8], oB[8];
    #pragma unroll
    for (int k = 0; k < 8; ++k) {
        float yd = pix0[k] + 128.0f;
        float vR = yd + 1.402f * pix2[k];
        float vG = yd - 0.34414f * pix1[k] - 0.71414f * pix2[k];
        float vB = yd + 1.772f * pix1[k];
        oR[k] = fminf(fmaxf(vR * (1.0f / 255.0f), 0.0f), 1.0f);
        oG[k] = fminf(fmaxf(vG * (1.0f / 255.0f), 0.0f), 1.0f);
        oB[k] = fminf(fmaxf(vB * (1.0f / 255.0f), 0.0f), 1.0f);
    }

    // ---- Stores: 3 planes x 2 float4, coalesced per instruction
    const size_t rowoff = (size_t)(row0 + rr) * 512 + col0 + blk * 8;
    float* qR = out + (size_t)(b * 3 + 0) * plane + rowoff;
    float* qG = out + (size_t)(b * 3 + 1) * plane + rowoff;
    float* qB = out + (size_t)(b * 3 + 2) * plane + rowoff;
    *(float4*)(qR)     = make_float4(oR[0], oR[1], oR[2], oR[3]);
    *(float4*)(qR + 4) = make_float4(oR[4], oR[5], oR[6], oR[7]);
    *(float4*)(qG)     = make_float4(oG[0], oG[1], oG[2], oG[3]);
    *(float4*)(qG + 4) = make_float4(oG[4], oG[5], oG[6], oG[7]);
    *(float4*)(qB)     = make_float4(oB[0], oB[1], oB[2], oB[3]);
    *(float4*)(qB + 4) = make_float4(oB[4], oB[5], oB[6], oB[7]);
}

extern "C" void kernel_launch(void* const* d_in, const int* in_sizes, int n_in,
                              void* d_out, int out_size, void* d_ws, size_t ws_size,
                              hipStream_t stream) {
    const float* img     = (const float*)d_in[0];
    const int*   quality = (const int*)d_in[1];
    float*       out     = (float*)d_out;
    // 16 images x 64 row-strips x 8 col-strips = 8192 strips, 1 wave each
    jpeg_fwd<<<8192, 64, 0, stream>>>(img, quality, out);
}

// Round 7
// 103.562 us; speedup vs baseline: 1.0220x; 1.0220x over previous
//
#include <hip/hip_runtime.h>
#include <math.h>

// Correctly-rounded double constants: Cj = cos(j*pi/16), N0 = sqrt(1/8).
#define C1 0.9807852804032304
#define C2 0.9238795325112867
#define C3 0.8314696123025452
#define C4 0.7071067811865476
#define C5 0.5555702330196022
#define C6 0.3826834323650898
#define C7 0.19509032201612825
#define N0 0.35355339059327373

// DCT-II matrix M[k][n] = norm_k * cos(pi/8*(n+0.5)*k), fully compile-time.
static constexpr double Mc[8][8] = {
 {  N0,      N0,      N0,      N0,      N0,      N0,      N0,      N0    },
 {  .5*C1,   .5*C3,   .5*C5,   .5*C7,  -.5*C7,  -.5*C5,  -.5*C3,  -.5*C1 },
 {  .5*C2,   .5*C6,  -.5*C6,  -.5*C2,  -.5*C2,  -.5*C6,   .5*C6,   .5*C2 },
 {  .5*C3,  -.5*C7,  -.5*C1,  -.5*C5,   .5*C5,   .5*C1,   .5*C7,  -.5*C3 },
 {  .5*C4,  -.5*C4,  -.5*C4,   .5*C4,   .5*C4,  -.5*C4,  -.5*C4,   .5*C4 },
 {  .5*C5,  -.5*C1,   .5*C7,   .5*C3,  -.5*C3,  -.5*C7,   .5*C1,  -.5*C5 },
 {  .5*C6,  -.5*C2,   .5*C2,  -.5*C6,  -.5*C6,   .5*C2,  -.5*C2,   .5*C6 },
 {  .5*C7,  -.5*C5,   .5*C3,  -.5*C1,   .5*C1,  -.5*C3,   .5*C5,  -.5*C7 },
};
// f32 copy for the post-quantization (smooth) path.
#define ROWF(r) {(float)Mc[r][0],(float)Mc[r][1],(float)Mc[r][2],(float)Mc[r][3],\
                 (float)Mc[r][4],(float)Mc[r][5],(float)Mc[r][6],(float)Mc[r][7]}
static constexpr float Mcf[8][8] = {ROWF(0),ROWF(1),ROWF(2),ROWF(3),ROWF(4),ROWF(5),ROWF(6),ROWF(7)};

// JPEG base quantization tables (exact integers)
static __device__ const double LUM_BASE[64] = {
 16,11,10,16,24,40,51,61,
 12,12,14,19,26,58,60,55,
 14,13,16,24,40,57,69,56,
 14,17,22,29,51,87,80,62,
 18,22,37,56,68,109,103,77,
 24,35,55,64,81,104,113,92,
 49,64,78,87,103,121,120,101,
 72,92,95,98,112,100,103,99};
static __device__ const double CHROM_BASE[64] = {
 17,18,24,47,99,99,99,99,
 18,21,26,66,99,99,99,99,
 24,26,56,99,99,99,99,99,
 47,66,99,99,99,99,99,99,
 99,99,99,99,99,99,99,99,
 99,99,99,99,99,99,99,99,
 99,99,99,99,99,99,99,99,
 99,99,99,99,99,99,99,99};

// Wave-level LDS fence: pins compiler ordering (memory clobber) AND drains
// LDS ops (lgkmcnt). Replaces __syncthreads() for 1-wave blocks. With the
// U64/U32 overlay (union), EVERY cross-phase LDS hazard pair is separated
// by one of these — correctness does not depend on TBAA. The memory clobber
// also pins the prefetch global-load issue point.
#define WAVE_FENCE() asm volatile("s_waitcnt lgkmcnt(0)" ::: "memory")

// Round 15 regressed (105.8; VGPR cap 102 < true peak ~110-125 -> spill).
// Round 16 (this): revert to __launch_bounds__(64,4); PERSISTENT 2-STRIP
// BLOCKS with prefetch:
// - grid 4096 = exactly 16 blocks/CU (the VGPR-128 residency cap): whole
//   grid resident in one generation, no launch churn.
// - strip 2*bid+1's 6 float4 loads issued after channel-0 of strip 2*bid
//   (~2000cy before use -> HBM latency fully hidden); rotated into the
//   working registers at iteration end (vmcnt wait lands there).
// - quant table built ONCE per block (4096 builds instead of 8192);
//   cold-start load stalls halved.
// Zero arithmetic change -> bit-identical output.
__global__ __launch_bounds__(64, 4) void jpeg_fwd(const float* __restrict__ img,
                                                  const int* __restrict__ quality,
                                                  float* __restrict__ out)
{
    __shared__ double QR[256];     // [2][8][8][2] = interleaved {q, 1/q}, 2048 B
    union UBuf {
        double d64[576];           // f64 transpose-1 view (pad-9), 4608 B
        float  f32[576];           // f32 transpose-2 view (pad-9), first 2304 B
    };
    __shared__ UBuf UB;            // overlaid: phases never simultaneously live

    const int l   = threadIdx.x;   // 0..63
    const int blk = l >> 3;        // block within strip (0..7)
    const int rr  = l & 7;         // row within block

    const size_t plane = 512 * 512;

    // Strip ids for this block: 2*bid and 2*bid+1 (8192 strips total).
    int sid = blockIdx.x << 1;

    // ---- Issue strip-0 loads early (my row's 8 px, all 3 planes, float4)
    const float* p0 = img + (size_t)((sid >> 9) * 3) * plane
                    + (size_t)((((sid & 511) >> 3) << 3) + rr) * 512
                    + ((sid & 7) << 6) + blk * 8;
    float4 Rc0 = *(const float4*)(p0);
    float4 Rc1 = *(const float4*)(p0 + 4);
    float4 Gc0 = *(const float4*)(p0 + plane);
    float4 Gc1 = *(const float4*)(p0 + plane + 4);
    float4 Bc0 = *(const float4*)(p0 + 2 * plane);
    float4 Bc1 = *(const float4*)(p0 + 2 * plane + 4);

    // ---- Build quant table + reciprocals in LDS — ONCE per block, all 64
    // lanes, 2 entries each. Cross-lane RAW protected by the wave fence.
    // Arithmetic identical to previous rounds -> bit-identical {q, 1/q}.
    {
        int q = quality[0];
        q = q < 1 ? 1 : (q > 100 ? 100 : q);
        double scale = (q < 50) ? (5000.0 / (double)q) : (200.0 - 2.0 * (double)q);
        #pragma unroll
        for (int h = 0; h < 2; ++h) {
            int e = l + (h << 6);           // entries l and l+64 -> covers 0..127
            int tbl = e >> 6, idx = e & 63;
            double base = tbl ? CHROM_BASE[idx] : LUM_BASE[idx];
            double v = (base * scale + 50.0) / 100.0;
            v = fmin(fmax(v, 1.0), 255.0);
            QR[2 * e]     = v;
            QR[2 * e + 1] = 1.0 / v;
        }
    }
    WAVE_FENCE();   // QR visible to all lanes; read-only from here on

    // YCbCr weights with x255 folded in at compile time (f64 products).
    const double F00 =  0.299 * 255.0,  F01 =  0.587 * 255.0,  F02 =  0.114 * 255.0;
    const double F10 = -0.1687 * 255.0, F11 = -0.3313 * 255.0, F12 =  0.5 * 255.0;
    const double F20 =  0.5 * 255.0,    F21 = -0.4187 * 255.0, F22 = -0.0813 * 255.0;

    // ================= per-channel pipeline (macro: CIDX is a literal) =====
    // LDS hazard ordering (overlay-safe): every conflicting pair below is
    // separated by a WAVE_FENCE:
    //   T1w(f64) |F| t1r(f64) |F| ... T2w(f32) |F| tCr(f32) |F| next T1w
#define CHANNEL_BODY(CIDX, PIXARR, COLOR_EXPR)                                  \
    {                                                                           \
        /* quant-table base for this channel (reference's flattened quirk) */   \
        const int sel_c = ((b * 3 + CIDX) < 16) ? 0 : 1;                        \
        const double* QRb = QR + (((sel_c << 6) + rr) << 1);                    \
        /* ---- Color convert (f64), keep +128 then -128 (both roundings) */   \
        double row[8];                                                          \
        _Pragma("unroll")                                                       \
        for (int k = 0; k < 8; ++k) {                                           \
            double rv = (double)rf[k];                                          \
            double gv = (double)gf[k];                                          \
            double bv = (double)bf[k];                                          \
            double v  = (COLOR_EXPR);                                           \
            row[k] = v - 128.0;                                                 \
        }                                                                       \
        /* ---- P1: row @ M^T via even-odd symmetry (f64) */                    \
        double y[8];                                                            \
        {                                                                       \
            double u0[4], v0[4];                                                \
            _Pragma("unroll")                                                   \
            for (int k = 0; k < 4; ++k) {                                       \
                u0[k] = row[k] + row[7 - k];                                    \
                v0[k] = row[k] - row[7 - k];                                    \
            }                                                                   \
            _Pragma("unroll")                                                   \
            for (int c = 0; c < 8; c += 2) {                                    \
                double se = 0.0, so = 0.0;                                      \
                _Pragma("unroll")                                               \
                for (int k = 0; k < 4; ++k) {                                   \
                    se += u0[k] * Mc[c][k];                                     \
                    so += v0[k] * Mc[c + 1][k];                                 \
                }                                                               \
                y[c] = se; y[c + 1] = so;                                       \
            }                                                                   \
        }                                                                       \
        /* ---- Transpose 1 (f64, pad-9, in-wave, fenced) */                    \
        {                                                                       \
            double* tb = UB.d64 + blk * 72 + rr * 9;                            \
            _Pragma("unroll")                                                   \
            for (int k = 0; k < 8; ++k) tb[k] = y[k];                           \
        }                                                                       \
        WAVE_FENCE();                                                           \
        double t1[8];                                                           \
        {                                                                       \
            const double* tb = UB.d64 + blk * 72 + rr;                          \
            _Pragma("unroll")                                                   \
            for (int k = 0; k < 8; ++k) t1[k] = tb[k * 9];                      \
        }                                                                       \
        WAVE_FENCE(); /* overlay WAR: T2 (f32) writes must stay below t1 reads */\
        /* ---- P2: column DCT (even-odd) + quantize tq = rint(s/q)*q.       */ \
        /* {q, 1/q} fetched per-j as one 16B LDS broadcast read (8 distinct  */ \
        /* addresses, 8-lane broadcast groups -> conflict-free).             */ \
        double wq[8];                                                           \
        {                                                                       \
            double tu[4], tv[4];                                                \
            _Pragma("unroll")                                                   \
            for (int k = 0; k < 4; ++k) {                                       \
                tu[k] = t1[k] + t1[7 - k];                                      \
                tv[k] = t1[k] - t1[7 - k];                                      \
            }                                                                   \
            _Pragma("unroll")                                                   \
            for (int j = 0; j < 8; j += 2) {                                    \
                double se = 0.0, so = 0.0;                                      \
                _Pragma("unroll")                                               \
                for (int k = 0; k < 4; ++k) {                                   \
                    se += tu[k] * Mc[j][k];                                     \
                    so += tv[k] * Mc[j + 1][k];                                 \
                }                                                               \
                { /* even j: Markstein reciprocal division, bit-identical */    \
                    double q = QRb[(j << 4)];                                   \
                    double r = QRb[(j << 4) + 1];                               \
                    double qh = se * r;                                         \
                    double e  = fma(-q, qh, se);                                \
                    double qq = fma(e, r, qh);                                  \
                    wq[j] = rint(qq) * q;                                       \
                }                                                               \
                { /* odd j */                                                   \
                    double q = QRb[((j + 1) << 4)];                             \
                    double r = QRb[((j + 1) << 4) + 1];                         \
                    double qh = so * r;                                         \
                    double e  = fma(-q, qh, so);                                \
                    double qq = fma(e, r, qh);                                  \
                    wq[j + 1] = rint(qq) * q;                                   \
                }                                                               \
            }                                                                   \
        }                                                                       \
        /* ======== post-cliff: f32 ======== */                                 \
        float wqf[8];                                                           \
        _Pragma("unroll")                                                       \
        for (int k = 0; k < 8; ++k) wqf[k] = (float)wq[k];                      \
        /* ---- P3: (tq^T row) @ M (f32, even-odd over output index j) */       \
        float a3[8];                                                            \
        _Pragma("unroll")                                                       \
        for (int j = 0; j < 4; ++j) {                                           \
            float pe = 0.0f, po = 0.0f;                                         \
            _Pragma("unroll")                                                   \
            for (int k = 0; k < 4; ++k) {                                       \
                pe += wqf[2 * k]     * Mcf[2 * k][j];                           \
                po += wqf[2 * k + 1] * Mcf[2 * k + 1][j];                       \
            }                                                                   \
            a3[j]     = pe + po;                                                \
            a3[7 - j] = pe - po;                                                \
        }                                                                       \
        /* ---- Transpose 2 (f32, pad-9, in-wave, fenced; overlaid buffer) */   \
        {                                                                       \
            float* tb = UB.f32 + blk * 72 + rr * 9;                             \
            _Pragma("unroll")                                                   \
            for (int k = 0; k < 8; ++k) tb[k] = a3[k];                          \
        }                                                                       \
        WAVE_FENCE();                                                           \
        float tC[8];                                                            \
        {                                                                       \
            const float* c2 = UB.f32 + blk * 72 + rr;                           \
            _Pragma("unroll")                                                   \
            for (int k = 0; k < 8; ++k) tC[k] = c2[k * 9];                      \
        }                                                                       \
        /* ---- P4 (f32, even-odd): final IDCT row rr for this channel */       \
        _Pragma("unroll")                                                       \
        for (int j = 0; j < 4; ++j) {                                           \
            float e = 0.0f, o = 0.0f;                                           \
            _Pragma("unroll")                                                   \
            for (int k = 0; k < 4; ++k) {                                       \
                e += tC[2 * k]     * Mcf[2 * k][j];                             \
                o += tC[2 * k + 1] * Mcf[2 * k + 1][j];                         \
            }                                                                   \
            PIXARR[j]     = e + o;                                              \
            PIXARR[7 - j] = e - o;                                              \
        }                                                                       \
        WAVE_FENCE(); /* WAR: next T1 (f64) writes stay below tC reads */       \
    }

    #pragma unroll 1
    for (int s = 0; s < 2; ++s, ++sid) {
        const int b    = sid >> 9;          // image index
        const int rem  = sid & 511;
        const int row0 = (rem >> 3) << 3;   // strip row * 8
        const int col0 = (rem & 7) << 6;    // strip col * 64

        float rf[8] = {Rc0.x, Rc0.y, Rc0.z, Rc0.w, Rc1.x, Rc1.y, Rc1.z, Rc1.w};
        float gf[8] = {Gc0.x, Gc0.y, Gc0.z, Gc0.w, Gc1.x, Gc1.y, Gc1.z, Gc1.w};
        float bf[8] = {Bc0.x, Bc0.y, Bc0.z, Bc0.w, Bc1.x, Bc1.y, Bc1.z, Bc1.w};

        float pix0[8], pix1[8], pix2[8];   // final IDCT pixel rows Y, Cb, Cr
        float4 Rn0, Rn1, Gn0, Gn1, Bn0, Bn1;

        CHANNEL_BODY(0, pix0, F00 * rv + F01 * gv + F02 * bv)

        // ---- Prefetch next strip AFTER channel 0 (~2000cy before use).
        // The WAVE_FENCE memory clobbers pin this issue point.
        if (s == 0) {
            const int sn = sid + 1;
            const float* pn = img + (size_t)((sn >> 9) * 3) * plane
                            + (size_t)((((sn & 511) >> 3) << 3) + rr) * 512
                            + ((sn & 7) << 6) + blk * 8;
            Rn0 = *(const float4*)(pn);
            Rn1 = *(const float4*)(pn + 4);
            Gn0 = *(const float4*)(pn + plane);
            Gn1 = *(const float4*)(pn + plane + 4);
            Bn0 = *(const float4*)(pn + 2 * plane);
            Bn1 = *(const float4*)(pn + 2 * plane + 4);
        }

        CHANNEL_BODY(1, pix1, F10 * rv + F11 * gv + F12 * bv + 128.0)
        CHANNEL_BODY(2, pix2, F20 * rv + F21 * gv + F22 * bv + 128.0)

        // ---- Color back (f32), all in registers; exact same expression trees.
        float oR[8], oG[8], oB[8];
        #pragma unroll
        for (int k = 0; k < 8; ++k) {
            float yd = pix0[k] + 128.0f;
            float vR = yd + 1.402f * pix2[k];
            float vG = yd - 0.34414f * pix1[k] - 0.71414f * pix2[k];
            float vB = yd + 1.772f * pix1[k];
            oR[k] = fminf(fmaxf(vR * (1.0f / 255.0f), 0.0f), 1.0f);
            oG[k] = fminf(fmaxf(vG * (1.0f / 255.0f), 0.0f), 1.0f);
            oB[k] = fminf(fmaxf(vB * (1.0f / 255.0f), 0.0f), 1.0f);
        }

        // ---- Stores: 3 planes x 2 float4, coalesced per instruction
        const size_t rowoff = (size_t)(row0 + rr) * 512 + col0 + blk * 8;
        float* qR = out + (size_t)(b * 3 + 0) * plane + rowoff;
        float* qG = out + (size_t)(b * 3 + 1) * plane + rowoff;
        float* qB = out + (size_t)(b * 3 + 2) * plane + rowoff;
        *(float4*)(qR)     = make_float4(oR[0], oR[1], oR[2], oR[3]);
        *(float4*)(qR + 4) = make_float4(oR[4], oR[5], oR[6], oR[7]);
        *(float4*)(qG)     = make_float4(oG[0], oG[1], oG[2], oG[3]);
        *(float4*)(qG + 4) = make_float4(oG[4], oG[5], oG[6], oG[7]);
        *(float4*)(qB)     = make_float4(oB[0], oB[1], oB[2], oB[3]);
        *(float4*)(qB + 4) = make_float4(oB[4], oB[5], oB[6], oB[7]);

        // ---- Rotate prefetched registers in (vmcnt wait lands HERE, long
        // after the loads completed under channels 1-2).
        if (s == 0) {
            Rc0 = Rn0; Rc1 = Rn1;
            Gc0 = Gn0; Gc1 = Gn1;
            Bc0 = Bn0; Bc1 = Bn1;
        }
    }
#undef CHANNEL_BODY
}

extern "C" void kernel_launch(void* const* d_in, const int* in_sizes, int n_in,
                              void* d_out, int out_size, void* d_ws, size_t ws_size,
                              hipStream_t stream) {
    const float* img     = (const float*)d_in[0];
    const int*   quality = (const int*)d_in[1];
    float*       out     = (float*)d_out;
    // 8192 strips, 2 per block: grid 4096 = exactly 16 blocks/CU resident
    jpeg_fwd<<<4096, 64, 0, stream>>>(img, quality, out);
}